// Round 8
// baseline (300.181 us; speedup 1.0000x reference)
//
#include <hip/hip_runtime.h>

// SpatialEncoding: out[src,dst] = b[min(path_len,5)-1], last-write-wins in p order.
//
// R17: INSTRUMENTED ROUND -- internal x2 repetition (REPS=2) in both kernels.
//   Purpose: in 7 rounds neither kernel has ever crossed the ~88us harness-
//   fill threshold, so rocprof top-5 has NEVER shown a per-kernel counter row
//   for the split pipeline; model vs residual disagree by ~80us. Both kernels
//   are idempotent (fully overwrite outputs), so running the body twice per
//   dispatch (a) doubles each dispatch's duration => >44us kernels enter the
//   top-5 WITH full counters, (b) bench delta vs R16 (255.7us) = bin+merge
//   exactly, (c) output unchanged.
//   Next round: REPS back to 1 + the fix the counters indicate.
//   KA se_bin_local<PAIRS,REPS>: R16 body, phases A-E wrapped in rep loop.
//   KC se_merge4<REPS>: R16 body, zero/walk/decode wrapped in rep loop.
//   Fallback (small ws): R9 pipeline verbatim (REPS=1 semantics).
//
//   rec(u32) = off(14 bits [31:18]) | (local_p+1)(15 bits [17:3]) | clamped(3)
//   merge key = (blk_rank(10) << 18) | (rec & 0x3FFFF)  (28 bits, >0 always)

#define BSHIFT 14
#define BCELLS (1 << BSHIFT)            // 16384 cells per bucket (64 KB region)
#define NBUCK  2198                     // ceil(36e6 / 16384)
#define NPACK  1100                     // ceil(NBUCK/2)+pad (in-bounds for owners)
#define NOWN   550                      // owner threads, 4 buckets each
#define BIN_THREADS 1024
#define TILE   12288                    // pairs per bin block (fallback path)
#define SCAN_TB 16                      // buckets per scan block (fallback)
#define MAXBLK 656                      // fallback scan LDS sizing
#define MRG_THREADS 1024
#define REPS   2                        // instrumentation: x2 internal repeat

__device__ __forceinline__ unsigned int unpack16(const unsigned int* A, unsigned int c) {
    return (A[c >> 1] >> ((c & 1) * 16)) & 0xFFFFu;
}

__device__ __forceinline__ float se_decode(unsigned int k,
                                           float b0, float b1, float b2,
                                           float b3, float b4) {
    unsigned c = k & 7u;
    float t = (c == 0u) ? b0 : (c == 1u) ? b1 : (c == 2u) ? b2 : (c == 3u) ? b3 : b4;
    return k ? t : 0.0f;
}

// ======================= FAST PATH =======================

// ---------------- KA: single-pass local binning, PAIRS/thread ----------------
template <int PAIRS, int NREP>
__global__ __launch_bounds__(BIN_THREADS, 8) void se_bin_local(
        const int* __restrict__ src_idx,
        const int* __restrict__ dst_idx,
        const int* __restrict__ path_len,
        unsigned int* __restrict__ recs,        // ws: [nblk][TILE_T] u32
        unsigned int* __restrict__ startsW,     // ws: [nblk][NPACK] u32 (u16 pairs)
        int P, int n) {
    constexpr int TILE_T = BIN_THREADS * PAIRS;
    __shared__ unsigned int histP[NPACK];       // local run starts (packed u16)
    __shared__ unsigned int curP[NPACK];        // counts
    __shared__ unsigned int stage[TILE_T];      // u32 staging
    __shared__ unsigned int scr[34];

    int t = threadIdx.x;
    int start = blockIdx.x * TILE_T;

    for (int rep = 0; rep < NREP; ++rep) {

    for (int i = t; i < NPACK; i += BIN_THREADS) curP[i] = 0u;
    __syncthreads();

    // Phase A: PAIRS pairs/thread (int4); cc = (cell<<3)|clamped
    unsigned int cc[PAIRS];
    unsigned int rk[PAIRS / 2];
#pragma unroll
    for (int j = 0; j < PAIRS / 4; ++j) {
        int base = start + j * (BIN_THREADS * 4) + t * 4;
        int k0 = j * 4;
        if (base + 3 < P) {
            int4 s = *reinterpret_cast<const int4*>(src_idx + base);
            int4 d = *reinterpret_cast<const int4*>(dst_idx + base);
            int4 l = *reinterpret_cast<const int4*>(path_len + base);
            cc[k0]     = ((unsigned int)(s.x * n + d.x) << 3) | (unsigned int)((l.x < 5 ? l.x : 5) - 1);
            cc[k0 + 1] = ((unsigned int)(s.y * n + d.y) << 3) | (unsigned int)((l.y < 5 ? l.y : 5) - 1);
            cc[k0 + 2] = ((unsigned int)(s.z * n + d.z) << 3) | (unsigned int)((l.z < 5 ? l.z : 5) - 1);
            cc[k0 + 3] = ((unsigned int)(s.w * n + d.w) << 3) | (unsigned int)((l.w < 5 ? l.w : 5) - 1);
        } else {
#pragma unroll
            for (int jj = 0; jj < 4; ++jj) {
                int p = base + jj;
                if (p < P) {
                    int len = path_len[p];
                    cc[k0 + jj] = ((unsigned int)(src_idx[p] * n + dst_idx[p]) << 3)
                                | (unsigned int)((len < 5 ? len : 5) - 1);
                } else {
                    cc[k0 + jj] = 0xFFFFFFFFu;
                }
            }
        }
    }
    // Histogram: atomicAdd return = within-bucket rank (< TILE_T < 2^16)
#pragma unroll
    for (int k = 0; k < PAIRS; ++k) {
        unsigned int rr = 0;
        if (cc[k] != 0xFFFFFFFFu) {
            unsigned int c = cc[k] >> 17;       // bucket = cell >> 14
            unsigned int old = atomicAdd(&curP[c >> 1], (c & 1) ? 0x10000u : 1u);
            rr = (old >> ((c & 1) * 16)) & 0xFFFFu;
        }
        if (k & 1) rk[k >> 1] |= rr << 16; else rk[k >> 1] = rr;
    }
    __syncthreads();

    // Phase B: block exclusive scan -> histP
    unsigned int l0 = 0, l1 = 0, l2v = 0, l3 = 0, s = 0;
    if (t < NOWN) {
        unsigned int w0 = curP[2 * t], w1 = curP[2 * t + 1];
        unsigned int v0 = w0 & 0xFFFFu, v1 = w0 >> 16;
        unsigned int v2 = w1 & 0xFFFFu, v3 = w1 >> 16;
        l0 = 0; l1 = v0; l2v = v0 + v1; l3 = v0 + v1 + v2;
        s = v0 + v1 + v2 + v3;
    }
    unsigned int x = s;
    for (int d = 1; d < 64; d <<= 1) {
        unsigned int y = (unsigned int)__shfl_up((int)x, d, 64);
        if ((t & 63) >= d) x += y;
    }
    if ((t & 63) == 63) scr[t >> 6] = x;
    __syncthreads();
    if (t == 0) {
        unsigned int acc = 0;
        for (int w = 0; w < 16; ++w) { unsigned int v = scr[w]; scr[16 + w] = acc; acc += v; }
        scr[32] = acc;
    }
    __syncthreads();
    unsigned int exc = x - s + scr[16 + (t >> 6)];
    if (t < NOWN) {
        unsigned int st0 = exc + l0, st1 = exc + l1, st2 = exc + l2v, st3 = exc + l3;
        histP[2 * t]     = (st0 & 0xFFFFu) | (st1 << 16);
        histP[2 * t + 1] = (st2 & 0xFFFFu) | (st3 << 16);
    }
    __syncthreads();

    // Phase C: persist local starts (coalesced)
    for (int i = t; i < NPACK; i += BIN_THREADS)
        startsW[(size_t)blockIdx.x * NPACK + i] = histP[i];

    // Phase D: pure stores at start[bucket] + rank
#pragma unroll
    for (int k = 0; k < PAIRS; ++k) {
        if (cc[k] != 0xFFFFFFFFu) {
            unsigned int c = cc[k] >> 17;
            unsigned int rank = (rk[k >> 1] >> ((k & 1) * 16)) & 0xFFFFu;
            unsigned int pos = unpack16(histP, c) + rank;
            unsigned int lp1 = (unsigned int)((k >> 2) * (BIN_THREADS * 4) + t * 4 + (k & 3) + 1);
            stage[pos] = (((cc[k] >> 3) & (BCELLS - 1)) << 18) | (lp1 << 3) | (cc[k] & 7u);
        }
    }
    __syncthreads();

    // Phase E: linear b128 flush
    unsigned int tot = scr[32];
    unsigned int* dst = recs + (size_t)blockIdx.x * TILE_T;
    const uint4* st4 = reinterpret_cast<const uint4*>(stage);
    uint4* dst4 = reinterpret_cast<uint4*>(dst);
    if (tot == TILE_T) {
#pragma unroll
        for (int j = 0; j < TILE_T / 4 / BIN_THREADS; ++j)
            dst4[j * BIN_THREADS + t] = st4[j * BIN_THREADS + t];
    } else {
        unsigned int tot4 = tot >> 2;
        for (unsigned int i = t; i < tot4; i += BIN_THREADS)
            dst4[i] = st4[i];
        for (unsigned int i = (tot4 << 2) + t; i < tot; i += BIN_THREADS)
            dst[i] = stage[i];
    }
    __syncthreads();                    // separate reps (stage reuse)

    }   // rep
}

// ---------------- KC: per-bucket merge, prefetched uint4 walk ----------------
template <int NREP>
__global__ __launch_bounds__(MRG_THREADS, 8) void se_merge4(
        const unsigned int* __restrict__ startsW,   // [nblk][NPACK] u32 (u16 pairs)
        const unsigned int* __restrict__ recs,      // [nblk][tileT]
        const float* __restrict__ b,
        float* __restrict__ out,
        long long totalCells, int nblk, int tileT) {
    __shared__ unsigned int tab[BCELLS];            // 64 KB

    // bijective XCD swizzle: consecutive c per XCD -> adjacent runs share L2 lines
    int orig = blockIdx.x;
    int q = gridDim.x >> 3, r8 = gridDim.x & 7;
    int xcd = orig & 7, idx = orig >> 3;
    int c = (xcd < r8 ? xcd * (q + 1) : r8 * (q + 1) + (xcd - r8) * q) + idx;

    long long baseCell = (long long)c << BSHIFT;
    long long rem = totalCells - baseCell;
    int valid = rem < BCELLS ? (int)rem : BCELLS;

    // run bounds read directly from startsW (L2-resident), issued BEFORE the
    // LDS zero so their latency hides under the fill loop.
    int tr = threadIdx.x;
    unsigned int st = 0, en = 0;
    if (tr < nblk) {
        const unsigned int* sw = startsW + (size_t)tr * NPACK;
        unsigned int w0 = sw[c >> 1];
        unsigned int w1 = sw[(c + 1) >> 1];
        st = (w0 >> ((c & 1) * 16)) & 0xFFFFu;
        en = (w1 >> (((c + 1) & 1) * 16)) & 0xFFFFu;
    }

    float b0 = b[0], b1 = b[1], b2 = b[2], b3 = b[3], b4 = b[4];
    uint4* tab4 = reinterpret_cast<uint4*>(tab);

    for (int rep = 0; rep < NREP; ++rep) {

    for (int i = threadIdx.x; i < BCELLS / 4; i += MRG_THREADS)
        tab4[i] = make_uint4(0u, 0u, 0u, 0u);
    __syncthreads();

    if (tr < nblk) {
        const uint4* rp4 =
            reinterpret_cast<const uint4*>(recs + (size_t)tr * tileT);
        unsigned int keyhi = (unsigned int)tr << 18;
        // aligned uint4 walk with next-group prefetch
        unsigned int i = st & ~3u;
        if (i < en) {
            uint4 cur = rp4[i >> 2];
            while (true) {
                unsigned int nx = i + 4;
                uint4 nxt;
                if (nx < en) nxt = rp4[nx >> 2];
                if (i     >= st && i     < en) atomicMax(&tab[cur.x >> 18], keyhi | (cur.x & 0x3FFFFu));
                if (i + 1 >= st && i + 1 < en) atomicMax(&tab[cur.y >> 18], keyhi | (cur.y & 0x3FFFFu));
                if (i + 2 >= st && i + 2 < en) atomicMax(&tab[cur.z >> 18], keyhi | (cur.z & 0x3FFFFu));
                if (i + 3 >= st && i + 3 < en) atomicMax(&tab[cur.w >> 18], keyhi | (cur.w & 0x3FFFFu));
                if (nx >= en) break;
                i = nx;
                cur = nxt;
            }
        }
    }
    __syncthreads();

    float* o = out + baseCell;
    int n4 = valid >> 2;
    float4* o4 = reinterpret_cast<float4*>(o);
    for (int i = threadIdx.x; i < n4; i += MRG_THREADS) {
        uint4 k = tab4[i];
        float4 v;
        v.x = se_decode(k.x, b0, b1, b2, b3, b4);
        v.y = se_decode(k.y, b0, b1, b2, b3, b4);
        v.z = se_decode(k.z, b0, b1, b2, b3, b4);
        v.w = se_decode(k.w, b0, b1, b2, b3, b4);
        o4[i] = v;
    }
    for (int i = (n4 << 2) + threadIdx.x; i < valid; i += MRG_THREADS)
        o[i] = se_decode(tab[i], b0, b1, b2, b3, b4);
    __syncthreads();                    // separate reps (tab reuse)

    }   // rep
}

// ======================= FALLBACK PATH (R9, verbatim) =======================

__global__ __launch_bounds__(BIN_THREADS) void se_hist(
        const int* __restrict__ src_idx,
        const int* __restrict__ dst_idx,
        unsigned int* __restrict__ countsW,      // [nblk][NPACK] u32 (u16 pairs)
        int P, int n) {
    __shared__ unsigned int curP[NPACK];
    int t = threadIdx.x;
    for (int i = t; i < NPACK; i += BIN_THREADS) curP[i] = 0u;
    __syncthreads();

    int start = blockIdx.x * TILE;
#pragma unroll
    for (int j = 0; j < 3; ++j) {
        int base = start + j * (BIN_THREADS * 4) + t * 4;
        if (base + 3 < P) {
            int4 s = *reinterpret_cast<const int4*>(src_idx + base);
            int4 d = *reinterpret_cast<const int4*>(dst_idx + base);
            unsigned int c0 = (unsigned int)(s.x * n + d.x) >> BSHIFT;
            unsigned int c1 = (unsigned int)(s.y * n + d.y) >> BSHIFT;
            unsigned int c2 = (unsigned int)(s.z * n + d.z) >> BSHIFT;
            unsigned int c3 = (unsigned int)(s.w * n + d.w) >> BSHIFT;
            atomicAdd(&curP[c0 >> 1], (c0 & 1) ? 0x10000u : 1u);
            atomicAdd(&curP[c1 >> 1], (c1 & 1) ? 0x10000u : 1u);
            atomicAdd(&curP[c2 >> 1], (c2 & 1) ? 0x10000u : 1u);
            atomicAdd(&curP[c3 >> 1], (c3 & 1) ? 0x10000u : 1u);
        } else {
            for (int p = base; p < P && p < base + 4; ++p) {
                unsigned int c = (unsigned int)(src_idx[p] * n + dst_idx[p]) >> BSHIFT;
                atomicAdd(&curP[c >> 1], (c & 1) ? 0x10000u : 1u);
            }
        }
    }
    __syncthreads();
    for (int i = t; i < NPACK; i += BIN_THREADS)
        countsW[(size_t)blockIdx.x * NPACK + i] = curP[i];
}

__global__ __launch_bounds__(256) void se_scan(
        unsigned int* __restrict__ countsW,   // in: counts, out: bases (in place)
        unsigned short* __restrict__ basesT,  // [NBUCK][nblk+1] u16, sentinel=total
        int nblk) {
    __shared__ unsigned short lds16[MAXBLK * SCAN_TB];   // 21 KB
    unsigned int* lds32 = reinterpret_cast<unsigned int*>(lds16);
    int t = threadIdx.x;
    int c0 = blockIdx.x * SCAN_TB;
    int w0 = c0 >> 1;
    int words = nblk * (SCAN_TB / 2);

    for (int i = t; i < words; i += 256) {
        int r = i >> 3, w = i & 7;
        if (w0 + w < NPACK)
            lds32[r * 8 + w] = countsW[(size_t)r * NPACK + w0 + w];
    }
    __syncthreads();

    if (t < SCAN_TB && c0 + t < NBUCK) {
        unsigned int acc = 0;
        for (int r = 0; r < nblk; ++r) {
            unsigned short v = lds16[r * SCAN_TB + t];
            lds16[r * SCAN_TB + t] = (unsigned short)acc;
            acc += v;
        }
        basesT[(size_t)(c0 + t) * (nblk + 1) + nblk] = (unsigned short)acc;
    }
    __syncthreads();

    for (int i = t; i < words; i += 256) {
        int r = i >> 3, w = i & 7;
        if (w0 + w < NPACK)
            countsW[(size_t)r * NPACK + w0 + w] = lds32[r * 8 + w];
    }
    for (int k = 0; k < SCAN_TB; ++k) {
        int c = c0 + k;
        if (c >= NBUCK) break;
        for (int r = t; r < nblk; r += 256)
            basesT[(size_t)c * (nblk + 1) + r] = lds16[r * SCAN_TB + k];
    }
}

__global__ __launch_bounds__(BIN_THREADS) void se_bin5(
        const int* __restrict__ src_idx,
        const int* __restrict__ dst_idx,
        const int* __restrict__ path_len,
        unsigned int* __restrict__ recs,         // d_out viewed as u32
        const unsigned int* __restrict__ basesW, // countsW after scan (u16 pairs)
        int P, int n) {
    __shared__ unsigned int histP[NPACK];
    __shared__ unsigned int curP[NPACK];
    __shared__ unsigned int gbaseP[NPACK];
    __shared__ unsigned int stage[TILE];
    __shared__ unsigned int scr[34];

    int t = threadIdx.x;
    int start = blockIdx.x * TILE;

    for (int i = t; i < NPACK; i += BIN_THREADS) curP[i] = 0u;
    __syncthreads();

    int cells[12];
    unsigned int lows[12];
#pragma unroll
    for (int j = 0; j < 3; ++j) {
        int base = start + j * (BIN_THREADS * 4) + t * 4;
        int k0 = j * 4;
        if (base + 3 < P) {
            int4 s = *reinterpret_cast<const int4*>(src_idx + base);
            int4 d = *reinterpret_cast<const int4*>(dst_idx + base);
            int4 l = *reinterpret_cast<const int4*>(path_len + base);
            int lp = base - start;
            cells[k0]     = s.x * n + d.x;
            cells[k0 + 1] = s.y * n + d.y;
            cells[k0 + 2] = s.z * n + d.z;
            cells[k0 + 3] = s.w * n + d.w;
            lows[k0]     = ((unsigned int)(lp + 1) << 3) | (unsigned int)((l.x < 5 ? l.x : 5) - 1);
            lows[k0 + 1] = ((unsigned int)(lp + 2) << 3) | (unsigned int)((l.y < 5 ? l.y : 5) - 1);
            lows[k0 + 2] = ((unsigned int)(lp + 3) << 3) | (unsigned int)((l.z < 5 ? l.z : 5) - 1);
            lows[k0 + 3] = ((unsigned int)(lp + 4) << 3) | (unsigned int)((l.w < 5 ? l.w : 5) - 1);
        } else {
#pragma unroll
            for (int jj = 0; jj < 4; ++jj) {
                int p = base + jj;
                if (p < P) {
                    cells[k0 + jj] = src_idx[p] * n + dst_idx[p];
                    int len = path_len[p];
                    int cl = (len < 5 ? len : 5) - 1;
                    lows[k0 + jj] = ((unsigned int)(p - start + 1) << 3) | (unsigned int)cl;
                } else {
                    cells[k0 + jj] = -1;
                    lows[k0 + jj] = 0u;
                }
            }
        }
    }
#pragma unroll
    for (int k = 0; k < 12; ++k) {
        if (cells[k] >= 0) {
            unsigned int c = (unsigned int)cells[k] >> BSHIFT;
            atomicAdd(&curP[c >> 1], (c & 1) ? 0x10000u : 1u);
        }
    }
    __syncthreads();

    unsigned int l0 = 0, l1 = 0, l2v = 0, l3 = 0, s = 0;
    if (t < NOWN) {
        unsigned int w0 = curP[2 * t], w1 = curP[2 * t + 1];
        unsigned int v0 = w0 & 0xFFFFu, v1 = w0 >> 16;
        unsigned int v2 = w1 & 0xFFFFu, v3 = w1 >> 16;
        l0 = 0; l1 = v0; l2v = v0 + v1; l3 = v0 + v1 + v2;
        s = v0 + v1 + v2 + v3;
    }
    unsigned int x = s;
    for (int d = 1; d < 64; d <<= 1) {
        unsigned int y = (unsigned int)__shfl_up((int)x, d, 64);
        if ((t & 63) >= d) x += y;
    }
    if ((t & 63) == 63) scr[t >> 6] = x;
    __syncthreads();
    if (t == 0) {
        unsigned int acc = 0;
        for (int w = 0; w < 16; ++w) { unsigned int v = scr[w]; scr[16 + w] = acc; acc += v; }
        scr[32] = acc;
    }
    __syncthreads();
    unsigned int exc = x - s + scr[16 + (t >> 6)];
    if (t < NOWN) {
        unsigned int st0 = exc + l0, st1 = exc + l1, st2 = exc + l2v, st3 = exc + l3;
        histP[2 * t]     = (st0 & 0xFFFFu) | (st1 << 16);
        histP[2 * t + 1] = (st2 & 0xFFFFu) | (st3 << 16);
    }
    __syncthreads();

    for (int i = t; i < NPACK; i += BIN_THREADS) {
        gbaseP[i] = basesW[(size_t)blockIdx.x * NPACK + i];
        curP[i] = histP[i];
    }
    __syncthreads();

#pragma unroll
    for (int k = 0; k < 12; ++k) {
        if (cells[k] >= 0) {
            unsigned int cell = (unsigned int)cells[k];
            unsigned int c = cell >> BSHIFT;
            unsigned int old = atomicAdd(&curP[c >> 1], (c & 1) ? 0x10000u : 1u);
            unsigned int pos = (old >> ((c & 1) * 16)) & 0xFFFFu;
            stage[pos] = ((cell & (BCELLS - 1)) << 18) | lows[k];
        }
    }
    __syncthreads();

    unsigned int tot = scr[32];
    for (unsigned int i = t; i < tot; i += BIN_THREADS) {
        unsigned int rec = stage[i];
        unsigned int lo = 0, hi = 2199;
        while (lo < hi) {
            unsigned int mid = (lo + hi + 1) >> 1;
            if (unpack16(histP, mid) <= i) lo = mid; else hi = mid - 1;
        }
        unsigned int c = lo;
        unsigned int pos = unpack16(gbaseP, c) + (i - unpack16(histP, c));
        recs[(size_t)c * BCELLS + pos] = rec;
    }
}

__global__ __launch_bounds__(MRG_THREADS) void se_merge(
        const unsigned short* __restrict__ basesT,  // [NBUCK][nblk+1]
        const float* __restrict__ b,
        float* __restrict__ out,              // same memory as recs
        long long totalCells, int nblk) {
    __shared__ unsigned int tab[BCELLS];

    int c = blockIdx.x;
    long long baseCell = (long long)c << BSHIFT;
    long long rem = totalCells - baseCell;
    int valid = rem < BCELLS ? (int)rem : BCELLS;

    uint4* tab4 = reinterpret_cast<uint4*>(tab);
    for (int i = threadIdx.x; i < BCELLS / 4; i += MRG_THREADS)
        tab4[i] = make_uint4(0u, 0u, 0u, 0u);
    __syncthreads();

    const unsigned int* r =
        reinterpret_cast<const unsigned int*>(out) + (size_t)c * BCELLS;
    int tr = threadIdx.x;
    if (tr < nblk) {
        const unsigned short* B = basesT + (size_t)c * (nblk + 1);
        unsigned int rb0 = B[tr], rb1 = B[tr + 1];
        unsigned int keyhi = (unsigned int)tr << 18;
        for (unsigned int i = rb0; i < rb1; ++i) {
            unsigned int rec = r[i];
            atomicMax(&tab[rec >> 18], keyhi | (rec & 0x3FFFFu));
        }
    }
    __syncthreads();

    float b0 = b[0], b1 = b[1], b2 = b[2], b3 = b[3], b4 = b[4];
    float* o = out + baseCell;
    int n4 = valid >> 2;
    float4* o4 = reinterpret_cast<float4*>(o);
    for (int i = threadIdx.x; i < n4; i += MRG_THREADS) {
        uint4 k = tab4[i];
        float4 v;
        v.x = se_decode(k.x, b0, b1, b2, b3, b4);
        v.y = se_decode(k.y, b0, b1, b2, b3, b4);
        v.z = se_decode(k.z, b0, b1, b2, b3, b4);
        v.w = se_decode(k.w, b0, b1, b2, b3, b4);
        o4[i] = v;
    }
    for (int i = (n4 << 2) + threadIdx.x; i < valid; i += MRG_THREADS)
        o[i] = se_decode(tab[i], b0, b1, b2, b3, b4);
}

// ======================= launch =======================

extern "C" void kernel_launch(void* const* d_in, const int* in_sizes, int n_in,
                              void* d_out, int out_size, void* d_ws, size_t ws_size,
                              hipStream_t stream) {
    // inputs: 0=x [N*128 f32], 1=b [5 f32], 2=src_idx [P i32], 3=dst_idx [P i32], 4=path_len [P i32]
    const float* b        = (const float*)d_in[1];
    const int*   src_idx  = (const int*)d_in[2];
    const int*   dst_idx  = (const int*)d_in[3];
    const int*   path_len = (const int*)d_in[4];
    int P = in_sizes[2];
    int n = in_sizes[0] / 128;                      // N = 6000
    long long totalCells = (long long)n * n;        // 36,000,000
    int nblk12 = (P + TILE - 1) / TILE;             // 652 (PAIRS=12 tiles)

    // PAIRS=8: TILE 8192, nblk 977 -> 95% grid packing
    const int TILE8 = BIN_THREADS * 8;
    int nblk8 = (P + TILE8 - 1) / TILE8;            // 977
    size_t need8  = (size_t)nblk8 * TILE8 * 4u + (size_t)nblk8 * NPACK * 4u;
    size_t need12 = (size_t)nblk12 * TILE * 4u + (size_t)nblk12 * NPACK * 4u;

    if (ws_size >= need8 && nblk8 <= MRG_THREADS) {
        unsigned int* recs    = (unsigned int*)d_ws;
        unsigned int* startsW = recs + (size_t)nblk8 * TILE8;

        se_bin_local<8, REPS><<<nblk8, BIN_THREADS, 0, stream>>>(
            src_idx, dst_idx, path_len, recs, startsW, P, n);

        se_merge4<REPS><<<NBUCK, MRG_THREADS, 0, stream>>>(
            startsW, recs, b, (float*)d_out, totalCells, nblk8, TILE8);
    } else if (ws_size >= need12 && nblk12 <= MRG_THREADS) {
        unsigned int* recs    = (unsigned int*)d_ws;
        unsigned int* startsW = recs + (size_t)nblk12 * TILE;

        se_bin_local<12, REPS><<<nblk12, BIN_THREADS, 0, stream>>>(
            src_idx, dst_idx, path_len, recs, startsW, P, n);

        se_merge4<REPS><<<NBUCK, MRG_THREADS, 0, stream>>>(
            startsW, recs, b, (float*)d_out, totalCells, nblk12, TILE);
    } else {
        // R9 fallback: records staged in d_out at global per-bucket bases
        unsigned int*   countsW = (unsigned int*)d_ws;
        unsigned short* basesT  = (unsigned short*)(countsW + (size_t)nblk12 * NPACK);

        se_hist<<<nblk12, BIN_THREADS, 0, stream>>>(src_idx, dst_idx, countsW, P, n);
        se_scan<<<(NBUCK + SCAN_TB - 1) / SCAN_TB, 256, 0, stream>>>(countsW, basesT, nblk12);
        se_bin5<<<nblk12, BIN_THREADS, 0, stream>>>(
            src_idx, dst_idx, path_len, (unsigned int*)d_out, countsW, P, n);
        se_merge<<<NBUCK, MRG_THREADS, 0, stream>>>(basesT, b, (float*)d_out,
                                                    totalCells, nblk12);
    }
}

// Round 9
// 255.439 us; speedup vs baseline: 1.1752x; 1.1752x over previous
//
#include <hip/hip_runtime.h>

// SpatialEncoding: out[src,dst] = b[min(path_len,5)-1], last-write-wins in p order.
//
// R18: R16 restored (REPS=1). R17's x2-instrumentation measured the split:
//   bin+merge = 44.5us COMBINED (300.2-255.7); the other ~211us of dur_us is
//   harness poison fills (~2x90us) + launch gaps, not controllable here.
//   Roofline: unavoidable HBM = 96MB input reads + 144MB output write =
//   240MB ~= 38us @6.3TB/s (intermediates are L3-resident). 44.5us = ~85% of
//   that floor; the residual ~6us is the band five structural experiments
//   (R12-R16) could not move. This is the terminal configuration.
//   KA se_bin_local<8>: single-atomic counting sort (rank from histogram
//       atomicAdd), pure-store placement, linear b128 flush, 95% grid pack.
//   KC se_merge4: direct L2 bounds read + prefetched predicated uint4 walk +
//       bijective XCD swizzle (R11's walk win preserved).
//   Fallback (small ws): R9 pipeline verbatim.
//
//   rec(u32) = off(14 bits [31:18]) | (local_p+1)(15 bits [17:3]) | clamped(3)
//   merge key = (blk_rank(10) << 18) | (rec & 0x3FFFF)  (28 bits, >0 always)

#define BSHIFT 14
#define BCELLS (1 << BSHIFT)            // 16384 cells per bucket (64 KB region)
#define NBUCK  2198                     // ceil(36e6 / 16384)
#define NPACK  1100                     // ceil(NBUCK/2)+pad (in-bounds for owners)
#define NOWN   550                      // owner threads, 4 buckets each
#define BIN_THREADS 1024
#define TILE   12288                    // pairs per bin block (fallback path)
#define SCAN_TB 16                      // buckets per scan block (fallback)
#define MAXBLK 656                      // fallback scan LDS sizing
#define MRG_THREADS 1024
#define REPS   1                        // instrumentation off (R17 measured with 2)

__device__ __forceinline__ unsigned int unpack16(const unsigned int* A, unsigned int c) {
    return (A[c >> 1] >> ((c & 1) * 16)) & 0xFFFFu;
}

__device__ __forceinline__ float se_decode(unsigned int k,
                                           float b0, float b1, float b2,
                                           float b3, float b4) {
    unsigned c = k & 7u;
    float t = (c == 0u) ? b0 : (c == 1u) ? b1 : (c == 2u) ? b2 : (c == 3u) ? b3 : b4;
    return k ? t : 0.0f;
}

// ======================= FAST PATH =======================

// ---------------- KA: single-pass local binning, PAIRS/thread ----------------
template <int PAIRS, int NREP>
__global__ __launch_bounds__(BIN_THREADS, 8) void se_bin_local(
        const int* __restrict__ src_idx,
        const int* __restrict__ dst_idx,
        const int* __restrict__ path_len,
        unsigned int* __restrict__ recs,        // ws: [nblk][TILE_T] u32
        unsigned int* __restrict__ startsW,     // ws: [nblk][NPACK] u32 (u16 pairs)
        int P, int n) {
    constexpr int TILE_T = BIN_THREADS * PAIRS;
    __shared__ unsigned int histP[NPACK];       // local run starts (packed u16)
    __shared__ unsigned int curP[NPACK];        // counts
    __shared__ unsigned int stage[TILE_T];      // u32 staging
    __shared__ unsigned int scr[34];

    int t = threadIdx.x;
    int start = blockIdx.x * TILE_T;

    for (int rep = 0; rep < NREP; ++rep) {

    for (int i = t; i < NPACK; i += BIN_THREADS) curP[i] = 0u;
    __syncthreads();

    // Phase A: PAIRS pairs/thread (int4); cc = (cell<<3)|clamped
    unsigned int cc[PAIRS];
    unsigned int rk[PAIRS / 2];
#pragma unroll
    for (int j = 0; j < PAIRS / 4; ++j) {
        int base = start + j * (BIN_THREADS * 4) + t * 4;
        int k0 = j * 4;
        if (base + 3 < P) {
            int4 s = *reinterpret_cast<const int4*>(src_idx + base);
            int4 d = *reinterpret_cast<const int4*>(dst_idx + base);
            int4 l = *reinterpret_cast<const int4*>(path_len + base);
            cc[k0]     = ((unsigned int)(s.x * n + d.x) << 3) | (unsigned int)((l.x < 5 ? l.x : 5) - 1);
            cc[k0 + 1] = ((unsigned int)(s.y * n + d.y) << 3) | (unsigned int)((l.y < 5 ? l.y : 5) - 1);
            cc[k0 + 2] = ((unsigned int)(s.z * n + d.z) << 3) | (unsigned int)((l.z < 5 ? l.z : 5) - 1);
            cc[k0 + 3] = ((unsigned int)(s.w * n + d.w) << 3) | (unsigned int)((l.w < 5 ? l.w : 5) - 1);
        } else {
#pragma unroll
            for (int jj = 0; jj < 4; ++jj) {
                int p = base + jj;
                if (p < P) {
                    int len = path_len[p];
                    cc[k0 + jj] = ((unsigned int)(src_idx[p] * n + dst_idx[p]) << 3)
                                | (unsigned int)((len < 5 ? len : 5) - 1);
                } else {
                    cc[k0 + jj] = 0xFFFFFFFFu;
                }
            }
        }
    }
    // Histogram: atomicAdd return = within-bucket rank (< TILE_T < 2^16)
#pragma unroll
    for (int k = 0; k < PAIRS; ++k) {
        unsigned int rr = 0;
        if (cc[k] != 0xFFFFFFFFu) {
            unsigned int c = cc[k] >> 17;       // bucket = cell >> 14
            unsigned int old = atomicAdd(&curP[c >> 1], (c & 1) ? 0x10000u : 1u);
            rr = (old >> ((c & 1) * 16)) & 0xFFFFu;
        }
        if (k & 1) rk[k >> 1] |= rr << 16; else rk[k >> 1] = rr;
    }
    __syncthreads();

    // Phase B: block exclusive scan -> histP
    unsigned int l0 = 0, l1 = 0, l2v = 0, l3 = 0, s = 0;
    if (t < NOWN) {
        unsigned int w0 = curP[2 * t], w1 = curP[2 * t + 1];
        unsigned int v0 = w0 & 0xFFFFu, v1 = w0 >> 16;
        unsigned int v2 = w1 & 0xFFFFu, v3 = w1 >> 16;
        l0 = 0; l1 = v0; l2v = v0 + v1; l3 = v0 + v1 + v2;
        s = v0 + v1 + v2 + v3;
    }
    unsigned int x = s;
    for (int d = 1; d < 64; d <<= 1) {
        unsigned int y = (unsigned int)__shfl_up((int)x, d, 64);
        if ((t & 63) >= d) x += y;
    }
    if ((t & 63) == 63) scr[t >> 6] = x;
    __syncthreads();
    if (t == 0) {
        unsigned int acc = 0;
        for (int w = 0; w < 16; ++w) { unsigned int v = scr[w]; scr[16 + w] = acc; acc += v; }
        scr[32] = acc;
    }
    __syncthreads();
    unsigned int exc = x - s + scr[16 + (t >> 6)];
    if (t < NOWN) {
        unsigned int st0 = exc + l0, st1 = exc + l1, st2 = exc + l2v, st3 = exc + l3;
        histP[2 * t]     = (st0 & 0xFFFFu) | (st1 << 16);
        histP[2 * t + 1] = (st2 & 0xFFFFu) | (st3 << 16);
    }
    __syncthreads();

    // Phase C: persist local starts (coalesced)
    for (int i = t; i < NPACK; i += BIN_THREADS)
        startsW[(size_t)blockIdx.x * NPACK + i] = histP[i];

    // Phase D: pure stores at start[bucket] + rank
#pragma unroll
    for (int k = 0; k < PAIRS; ++k) {
        if (cc[k] != 0xFFFFFFFFu) {
            unsigned int c = cc[k] >> 17;
            unsigned int rank = (rk[k >> 1] >> ((k & 1) * 16)) & 0xFFFFu;
            unsigned int pos = unpack16(histP, c) + rank;
            unsigned int lp1 = (unsigned int)((k >> 2) * (BIN_THREADS * 4) + t * 4 + (k & 3) + 1);
            stage[pos] = (((cc[k] >> 3) & (BCELLS - 1)) << 18) | (lp1 << 3) | (cc[k] & 7u);
        }
    }
    __syncthreads();

    // Phase E: linear b128 flush
    unsigned int tot = scr[32];
    unsigned int* dst = recs + (size_t)blockIdx.x * TILE_T;
    const uint4* st4 = reinterpret_cast<const uint4*>(stage);
    uint4* dst4 = reinterpret_cast<uint4*>(dst);
    if (tot == TILE_T) {
#pragma unroll
        for (int j = 0; j < TILE_T / 4 / BIN_THREADS; ++j)
            dst4[j * BIN_THREADS + t] = st4[j * BIN_THREADS + t];
    } else {
        unsigned int tot4 = tot >> 2;
        for (unsigned int i = t; i < tot4; i += BIN_THREADS)
            dst4[i] = st4[i];
        for (unsigned int i = (tot4 << 2) + t; i < tot; i += BIN_THREADS)
            dst[i] = stage[i];
    }
    __syncthreads();                    // separate reps (stage reuse)

    }   // rep
}

// ---------------- KC: per-bucket merge, prefetched uint4 walk ----------------
template <int NREP>
__global__ __launch_bounds__(MRG_THREADS, 8) void se_merge4(
        const unsigned int* __restrict__ startsW,   // [nblk][NPACK] u32 (u16 pairs)
        const unsigned int* __restrict__ recs,      // [nblk][tileT]
        const float* __restrict__ b,
        float* __restrict__ out,
        long long totalCells, int nblk, int tileT) {
    __shared__ unsigned int tab[BCELLS];            // 64 KB

    // bijective XCD swizzle: consecutive c per XCD -> adjacent runs share L2 lines
    int orig = blockIdx.x;
    int q = gridDim.x >> 3, r8 = gridDim.x & 7;
    int xcd = orig & 7, idx = orig >> 3;
    int c = (xcd < r8 ? xcd * (q + 1) : r8 * (q + 1) + (xcd - r8) * q) + idx;

    long long baseCell = (long long)c << BSHIFT;
    long long rem = totalCells - baseCell;
    int valid = rem < BCELLS ? (int)rem : BCELLS;

    // run bounds read directly from startsW (L2-resident), issued BEFORE the
    // LDS zero so their latency hides under the fill loop.
    int tr = threadIdx.x;
    unsigned int st = 0, en = 0;
    if (tr < nblk) {
        const unsigned int* sw = startsW + (size_t)tr * NPACK;
        unsigned int w0 = sw[c >> 1];
        unsigned int w1 = sw[(c + 1) >> 1];
        st = (w0 >> ((c & 1) * 16)) & 0xFFFFu;
        en = (w1 >> (((c + 1) & 1) * 16)) & 0xFFFFu;
    }

    float b0 = b[0], b1 = b[1], b2 = b[2], b3 = b[3], b4 = b[4];
    uint4* tab4 = reinterpret_cast<uint4*>(tab);

    for (int rep = 0; rep < NREP; ++rep) {

    for (int i = threadIdx.x; i < BCELLS / 4; i += MRG_THREADS)
        tab4[i] = make_uint4(0u, 0u, 0u, 0u);
    __syncthreads();

    if (tr < nblk) {
        const uint4* rp4 =
            reinterpret_cast<const uint4*>(recs + (size_t)tr * tileT);
        unsigned int keyhi = (unsigned int)tr << 18;
        // aligned uint4 walk with next-group prefetch
        unsigned int i = st & ~3u;
        if (i < en) {
            uint4 cur = rp4[i >> 2];
            while (true) {
                unsigned int nx = i + 4;
                uint4 nxt;
                if (nx < en) nxt = rp4[nx >> 2];
                if (i     >= st && i     < en) atomicMax(&tab[cur.x >> 18], keyhi | (cur.x & 0x3FFFFu));
                if (i + 1 >= st && i + 1 < en) atomicMax(&tab[cur.y >> 18], keyhi | (cur.y & 0x3FFFFu));
                if (i + 2 >= st && i + 2 < en) atomicMax(&tab[cur.z >> 18], keyhi | (cur.z & 0x3FFFFu));
                if (i + 3 >= st && i + 3 < en) atomicMax(&tab[cur.w >> 18], keyhi | (cur.w & 0x3FFFFu));
                if (nx >= en) break;
                i = nx;
                cur = nxt;
            }
        }
    }
    __syncthreads();

    float* o = out + baseCell;
    int n4 = valid >> 2;
    float4* o4 = reinterpret_cast<float4*>(o);
    for (int i = threadIdx.x; i < n4; i += MRG_THREADS) {
        uint4 k = tab4[i];
        float4 v;
        v.x = se_decode(k.x, b0, b1, b2, b3, b4);
        v.y = se_decode(k.y, b0, b1, b2, b3, b4);
        v.z = se_decode(k.z, b0, b1, b2, b3, b4);
        v.w = se_decode(k.w, b0, b1, b2, b3, b4);
        o4[i] = v;
    }
    for (int i = (n4 << 2) + threadIdx.x; i < valid; i += MRG_THREADS)
        o[i] = se_decode(tab[i], b0, b1, b2, b3, b4);
    __syncthreads();                    // separate reps (tab reuse)

    }   // rep
}

// ======================= FALLBACK PATH (R9, verbatim) =======================

__global__ __launch_bounds__(BIN_THREADS) void se_hist(
        const int* __restrict__ src_idx,
        const int* __restrict__ dst_idx,
        unsigned int* __restrict__ countsW,      // [nblk][NPACK] u32 (u16 pairs)
        int P, int n) {
    __shared__ unsigned int curP[NPACK];
    int t = threadIdx.x;
    for (int i = t; i < NPACK; i += BIN_THREADS) curP[i] = 0u;
    __syncthreads();

    int start = blockIdx.x * TILE;
#pragma unroll
    for (int j = 0; j < 3; ++j) {
        int base = start + j * (BIN_THREADS * 4) + t * 4;
        if (base + 3 < P) {
            int4 s = *reinterpret_cast<const int4*>(src_idx + base);
            int4 d = *reinterpret_cast<const int4*>(dst_idx + base);
            unsigned int c0 = (unsigned int)(s.x * n + d.x) >> BSHIFT;
            unsigned int c1 = (unsigned int)(s.y * n + d.y) >> BSHIFT;
            unsigned int c2 = (unsigned int)(s.z * n + d.z) >> BSHIFT;
            unsigned int c3 = (unsigned int)(s.w * n + d.w) >> BSHIFT;
            atomicAdd(&curP[c0 >> 1], (c0 & 1) ? 0x10000u : 1u);
            atomicAdd(&curP[c1 >> 1], (c1 & 1) ? 0x10000u : 1u);
            atomicAdd(&curP[c2 >> 1], (c2 & 1) ? 0x10000u : 1u);
            atomicAdd(&curP[c3 >> 1], (c3 & 1) ? 0x10000u : 1u);
        } else {
            for (int p = base; p < P && p < base + 4; ++p) {
                unsigned int c = (unsigned int)(src_idx[p] * n + dst_idx[p]) >> BSHIFT;
                atomicAdd(&curP[c >> 1], (c & 1) ? 0x10000u : 1u);
            }
        }
    }
    __syncthreads();
    for (int i = t; i < NPACK; i += BIN_THREADS)
        countsW[(size_t)blockIdx.x * NPACK + i] = curP[i];
}

__global__ __launch_bounds__(256) void se_scan(
        unsigned int* __restrict__ countsW,   // in: counts, out: bases (in place)
        unsigned short* __restrict__ basesT,  // [NBUCK][nblk+1] u16, sentinel=total
        int nblk) {
    __shared__ unsigned short lds16[MAXBLK * SCAN_TB];   // 21 KB
    unsigned int* lds32 = reinterpret_cast<unsigned int*>(lds16);
    int t = threadIdx.x;
    int c0 = blockIdx.x * SCAN_TB;
    int w0 = c0 >> 1;
    int words = nblk * (SCAN_TB / 2);

    for (int i = t; i < words; i += 256) {
        int r = i >> 3, w = i & 7;
        if (w0 + w < NPACK)
            lds32[r * 8 + w] = countsW[(size_t)r * NPACK + w0 + w];
    }
    __syncthreads();

    if (t < SCAN_TB && c0 + t < NBUCK) {
        unsigned int acc = 0;
        for (int r = 0; r < nblk; ++r) {
            unsigned short v = lds16[r * SCAN_TB + t];
            lds16[r * SCAN_TB + t] = (unsigned short)acc;
            acc += v;
        }
        basesT[(size_t)(c0 + t) * (nblk + 1) + nblk] = (unsigned short)acc;
    }
    __syncthreads();

    for (int i = t; i < words; i += 256) {
        int r = i >> 3, w = i & 7;
        if (w0 + w < NPACK)
            countsW[(size_t)r * NPACK + w0 + w] = lds32[r * 8 + w];
    }
    for (int k = 0; k < SCAN_TB; ++k) {
        int c = c0 + k;
        if (c >= NBUCK) break;
        for (int r = t; r < nblk; r += 256)
            basesT[(size_t)c * (nblk + 1) + r] = lds16[r * SCAN_TB + k];
    }
}

__global__ __launch_bounds__(BIN_THREADS) void se_bin5(
        const int* __restrict__ src_idx,
        const int* __restrict__ dst_idx,
        const int* __restrict__ path_len,
        unsigned int* __restrict__ recs,         // d_out viewed as u32
        const unsigned int* __restrict__ basesW, // countsW after scan (u16 pairs)
        int P, int n) {
    __shared__ unsigned int histP[NPACK];
    __shared__ unsigned int curP[NPACK];
    __shared__ unsigned int gbaseP[NPACK];
    __shared__ unsigned int stage[TILE];
    __shared__ unsigned int scr[34];

    int t = threadIdx.x;
    int start = blockIdx.x * TILE;

    for (int i = t; i < NPACK; i += BIN_THREADS) curP[i] = 0u;
    __syncthreads();

    int cells[12];
    unsigned int lows[12];
#pragma unroll
    for (int j = 0; j < 3; ++j) {
        int base = start + j * (BIN_THREADS * 4) + t * 4;
        int k0 = j * 4;
        if (base + 3 < P) {
            int4 s = *reinterpret_cast<const int4*>(src_idx + base);
            int4 d = *reinterpret_cast<const int4*>(dst_idx + base);
            int4 l = *reinterpret_cast<const int4*>(path_len + base);
            int lp = base - start;
            cells[k0]     = s.x * n + d.x;
            cells[k0 + 1] = s.y * n + d.y;
            cells[k0 + 2] = s.z * n + d.z;
            cells[k0 + 3] = s.w * n + d.w;
            lows[k0]     = ((unsigned int)(lp + 1) << 3) | (unsigned int)((l.x < 5 ? l.x : 5) - 1);
            lows[k0 + 1] = ((unsigned int)(lp + 2) << 3) | (unsigned int)((l.y < 5 ? l.y : 5) - 1);
            lows[k0 + 2] = ((unsigned int)(lp + 3) << 3) | (unsigned int)((l.z < 5 ? l.z : 5) - 1);
            lows[k0 + 3] = ((unsigned int)(lp + 4) << 3) | (unsigned int)((l.w < 5 ? l.w : 5) - 1);
        } else {
#pragma unroll
            for (int jj = 0; jj < 4; ++jj) {
                int p = base + jj;
                if (p < P) {
                    cells[k0 + jj] = src_idx[p] * n + dst_idx[p];
                    int len = path_len[p];
                    int cl = (len < 5 ? len : 5) - 1;
                    lows[k0 + jj] = ((unsigned int)(p - start + 1) << 3) | (unsigned int)cl;
                } else {
                    cells[k0 + jj] = -1;
                    lows[k0 + jj] = 0u;
                }
            }
        }
    }
#pragma unroll
    for (int k = 0; k < 12; ++k) {
        if (cells[k] >= 0) {
            unsigned int c = (unsigned int)cells[k] >> BSHIFT;
            atomicAdd(&curP[c >> 1], (c & 1) ? 0x10000u : 1u);
        }
    }
    __syncthreads();

    unsigned int l0 = 0, l1 = 0, l2v = 0, l3 = 0, s = 0;
    if (t < NOWN) {
        unsigned int w0 = curP[2 * t], w1 = curP[2 * t + 1];
        unsigned int v0 = w0 & 0xFFFFu, v1 = w0 >> 16;
        unsigned int v2 = w1 & 0xFFFFu, v3 = w1 >> 16;
        l0 = 0; l1 = v0; l2v = v0 + v1; l3 = v0 + v1 + v2;
        s = v0 + v1 + v2 + v3;
    }
    unsigned int x = s;
    for (int d = 1; d < 64; d <<= 1) {
        unsigned int y = (unsigned int)__shfl_up((int)x, d, 64);
        if ((t & 63) >= d) x += y;
    }
    if ((t & 63) == 63) scr[t >> 6] = x;
    __syncthreads();
    if (t == 0) {
        unsigned int acc = 0;
        for (int w = 0; w < 16; ++w) { unsigned int v = scr[w]; scr[16 + w] = acc; acc += v; }
        scr[32] = acc;
    }
    __syncthreads();
    unsigned int exc = x - s + scr[16 + (t >> 6)];
    if (t < NOWN) {
        unsigned int st0 = exc + l0, st1 = exc + l1, st2 = exc + l2v, st3 = exc + l3;
        histP[2 * t]     = (st0 & 0xFFFFu) | (st1 << 16);
        histP[2 * t + 1] = (st2 & 0xFFFFu) | (st3 << 16);
    }
    __syncthreads();

    for (int i = t; i < NPACK; i += BIN_THREADS) {
        gbaseP[i] = basesW[(size_t)blockIdx.x * NPACK + i];
        curP[i] = histP[i];
    }
    __syncthreads();

#pragma unroll
    for (int k = 0; k < 12; ++k) {
        if (cells[k] >= 0) {
            unsigned int cell = (unsigned int)cells[k];
            unsigned int c = cell >> BSHIFT;
            unsigned int old = atomicAdd(&curP[c >> 1], (c & 1) ? 0x10000u : 1u);
            unsigned int pos = (old >> ((c & 1) * 16)) & 0xFFFFu;
            stage[pos] = ((cell & (BCELLS - 1)) << 18) | lows[k];
        }
    }
    __syncthreads();

    unsigned int tot = scr[32];
    for (unsigned int i = t; i < tot; i += BIN_THREADS) {
        unsigned int rec = stage[i];
        unsigned int lo = 0, hi = 2199;
        while (lo < hi) {
            unsigned int mid = (lo + hi + 1) >> 1;
            if (unpack16(histP, mid) <= i) lo = mid; else hi = mid - 1;
        }
        unsigned int c = lo;
        unsigned int pos = unpack16(gbaseP, c) + (i - unpack16(histP, c));
        recs[(size_t)c * BCELLS + pos] = rec;
    }
}

__global__ __launch_bounds__(MRG_THREADS) void se_merge(
        const unsigned short* __restrict__ basesT,  // [NBUCK][nblk+1]
        const float* __restrict__ b,
        float* __restrict__ out,              // same memory as recs
        long long totalCells, int nblk) {
    __shared__ unsigned int tab[BCELLS];

    int c = blockIdx.x;
    long long baseCell = (long long)c << BSHIFT;
    long long rem = totalCells - baseCell;
    int valid = rem < BCELLS ? (int)rem : BCELLS;

    uint4* tab4 = reinterpret_cast<uint4*>(tab);
    for (int i = threadIdx.x; i < BCELLS / 4; i += MRG_THREADS)
        tab4[i] = make_uint4(0u, 0u, 0u, 0u);
    __syncthreads();

    const unsigned int* r =
        reinterpret_cast<const unsigned int*>(out) + (size_t)c * BCELLS;
    int tr = threadIdx.x;
    if (tr < nblk) {
        const unsigned short* B = basesT + (size_t)c * (nblk + 1);
        unsigned int rb0 = B[tr], rb1 = B[tr + 1];
        unsigned int keyhi = (unsigned int)tr << 18;
        for (unsigned int i = rb0; i < rb1; ++i) {
            unsigned int rec = r[i];
            atomicMax(&tab[rec >> 18], keyhi | (rec & 0x3FFFFu));
        }
    }
    __syncthreads();

    float b0 = b[0], b1 = b[1], b2 = b[2], b3 = b[3], b4 = b[4];
    float* o = out + baseCell;
    int n4 = valid >> 2;
    float4* o4 = reinterpret_cast<float4*>(o);
    for (int i = threadIdx.x; i < n4; i += MRG_THREADS) {
        uint4 k = tab4[i];
        float4 v;
        v.x = se_decode(k.x, b0, b1, b2, b3, b4);
        v.y = se_decode(k.y, b0, b1, b2, b3, b4);
        v.z = se_decode(k.z, b0, b1, b2, b3, b4);
        v.w = se_decode(k.w, b0, b1, b2, b3, b4);
        o4[i] = v;
    }
    for (int i = (n4 << 2) + threadIdx.x; i < valid; i += MRG_THREADS)
        o[i] = se_decode(tab[i], b0, b1, b2, b3, b4);
}

// ======================= launch =======================

extern "C" void kernel_launch(void* const* d_in, const int* in_sizes, int n_in,
                              void* d_out, int out_size, void* d_ws, size_t ws_size,
                              hipStream_t stream) {
    // inputs: 0=x [N*128 f32], 1=b [5 f32], 2=src_idx [P i32], 3=dst_idx [P i32], 4=path_len [P i32]
    const float* b        = (const float*)d_in[1];
    const int*   src_idx  = (const int*)d_in[2];
    const int*   dst_idx  = (const int*)d_in[3];
    const int*   path_len = (const int*)d_in[4];
    int P = in_sizes[2];
    int n = in_sizes[0] / 128;                      // N = 6000
    long long totalCells = (long long)n * n;        // 36,000,000
    int nblk12 = (P + TILE - 1) / TILE;             // 652 (PAIRS=12 tiles)

    // PAIRS=8: TILE 8192, nblk 977 -> 95% grid packing
    const int TILE8 = BIN_THREADS * 8;
    int nblk8 = (P + TILE8 - 1) / TILE8;            // 977
    size_t need8  = (size_t)nblk8 * TILE8 * 4u + (size_t)nblk8 * NPACK * 4u;
    size_t need12 = (size_t)nblk12 * TILE * 4u + (size_t)nblk12 * NPACK * 4u;

    if (ws_size >= need8 && nblk8 <= MRG_THREADS) {
        unsigned int* recs    = (unsigned int*)d_ws;
        unsigned int* startsW = recs + (size_t)nblk8 * TILE8;

        se_bin_local<8, REPS><<<nblk8, BIN_THREADS, 0, stream>>>(
            src_idx, dst_idx, path_len, recs, startsW, P, n);

        se_merge4<REPS><<<NBUCK, MRG_THREADS, 0, stream>>>(
            startsW, recs, b, (float*)d_out, totalCells, nblk8, TILE8);
    } else if (ws_size >= need12 && nblk12 <= MRG_THREADS) {
        unsigned int* recs    = (unsigned int*)d_ws;
        unsigned int* startsW = recs + (size_t)nblk12 * TILE;

        se_bin_local<12, REPS><<<nblk12, BIN_THREADS, 0, stream>>>(
            src_idx, dst_idx, path_len, recs, startsW, P, n);

        se_merge4<REPS><<<NBUCK, MRG_THREADS, 0, stream>>>(
            startsW, recs, b, (float*)d_out, totalCells, nblk12, TILE);
    } else {
        // R9 fallback: records staged in d_out at global per-bucket bases
        unsigned int*   countsW = (unsigned int*)d_ws;
        unsigned short* basesT  = (unsigned short*)(countsW + (size_t)nblk12 * NPACK);

        se_hist<<<nblk12, BIN_THREADS, 0, stream>>>(src_idx, dst_idx, countsW, P, n);
        se_scan<<<(NBUCK + SCAN_TB - 1) / SCAN_TB, 256, 0, stream>>>(countsW, basesT, nblk12);
        se_bin5<<<nblk12, BIN_THREADS, 0, stream>>>(
            src_idx, dst_idx, path_len, (unsigned int*)d_out, countsW, P, n);
        se_merge<<<NBUCK, MRG_THREADS, 0, stream>>>(basesT, b, (float*)d_out,
                                                    totalCells, nblk12);
    }
}